// Round 10
// baseline (93.874 us; speedup 1.0000x reference)
//
#include <hip/hip_runtime.h>

// Problem constants (from reference setup_inputs)
#define QDIM 900
#define CDIM 80
#define TDIM 300
#define QPB 36               // q's per block (4 waves x 9)
#define QPW 9                // q's per wave
#define NQB (QDIM / QPB)     // 25 blocks per batch

typedef float floatx2 __attribute__((ext_vector_type(2)));
typedef float floatx4 __attribute__((ext_vector_type(4)));

// ---- VOP3P packed-f32 (gfx950 has pk_add/pk_mul/pk_fma only; NO pk_min/max) ----
__device__ __forceinline__ floatx2 pk_add(floatx2 a, floatx2 b) {
    floatx2 d; asm("v_pk_add_f32 %0, %1, %2" : "=v"(d) : "v"(a), "v"(b)); return d;
}
__device__ __forceinline__ floatx2 pk_fma(floatx2 a, floatx2 b, floatx2 c) {
    floatx2 d; asm("v_pk_fma_f32 %0, %1, %2, %3" : "=v"(d) : "v"(a), "v"(b), "v"(c)); return d;
}

// Target state (x,y packed per field; p0 stored NEGATED so max(p0) -> min(p0n))
struct TgtReg {
    floatx2 p0n;   // (-x0, -y0)
    floatx2 p1;    // ( x1,  y1)
    floatx2 wh;    // ( w,   h )
    floatx2 cc;    // ( cx,  cy)
    float   area;
    int     lab4;  // label * 4 (byte offset into cls row)
};

// cost = (2 - 2*sigmoid) + 5*L1 - 2*(inter/uni + uni/areac)
// cwh = (awh + bwh) - iwr (enclosing identity); iwr = unclamped overlap
__device__ __forceinline__ float cost_one(
    floatx2 ap0n, floatx2 ap1, floatx2 awh, floatx2 acc2, float area_a,
    floatx2 neg1,
    const float* __restrict__ cls_j, const TgtReg& t)
{
    float clsv = *(const float*)((const char*)cls_j + t.lab4);

    // scalar min/max (no packed f32 min/max on gfx950)
    floatx2 M0n, m1;
    M0n.x = fminf(ap0n.x, t.p0n.x);
    M0n.y = fminf(ap0n.y, t.p0n.y);
    m1.x  = fminf(ap1.x,  t.p1.x);
    m1.y  = fminf(ap1.y,  t.p1.y);

    floatx2 iwr = pk_add(m1, M0n);            // m1 - M0
    float iw = fmaxf(iwr.x, 0.0f);
    float ih = fmaxf(iwr.y, 0.0f);

    floatx2 swh = pk_add(awh, t.wh);
    floatx2 cwh = pk_fma(iwr, neg1, swh);     // swh - iwr
    floatx2 dcc = pk_fma(t.cc, neg1, acc2);   // acc2 - t.cc
    floatx2 dwh = pk_fma(t.wh, neg1, awh);    // awh - t.wh

    float inter = iw * ih;
    float areac = cwh.x * cwh.y;
    float uni   = (area_a + t.area) - inter;

    // inter/uni + uni/areac = (inter*areac + uni^2)/(uni*areac) -- one rcp
    float num   = fmaf(uni, uni, inter * areac);
    float den   = uni * areac;
    float ratio = num * __builtin_amdgcn_rcpf(den);

    float l1 = (fabsf(dcc.x) + fabsf(dcc.y)) + (fabsf(dwh.x) + fabsf(dwh.y));

    float acc = fmaf(5.0f, l1, clsv);
    return fmaf(-2.0f, ratio, acc);
}

__device__ __forceinline__ TgtReg load_tgt(const float4* tb4, const int* lb, int t)
{
    TgtReg r;
    float4 v = tb4[t];
    float hw = 0.5f * v.z, hh = 0.5f * v.w;
    r.p0n = (floatx2){hw - v.x, hh - v.y};    // -(cx-hw), -(cy-hh)
    r.p1  = (floatx2){v.x + hw, v.y + hh};
    r.wh  = (floatx2){v.z, v.w};
    r.cc  = (floatx2){v.x, v.y};
    r.area = v.z * v.w;
    r.lab4 = lb[t] << 2;
    return r;
}

__global__ __launch_bounds__(256, 4) void matcher_cost_kernel(
    const float* __restrict__ pred_logits,  // [B,Q,C]
    const float* __restrict__ pred_boxes,   // [B,Q,4] cxcywh
    const int*   __restrict__ tgt_labels,   // [B,T]
    const float* __restrict__ tgt_boxes,    // [B,T,4] cxcywh
    float* __restrict__ out)                // [B,Q,T]
{
    // s_cls[ql*C + c] = 2 - 2*sigmoid(logit) = 2/(1+e^x)
    __shared__ float s_cls[QPB * CDIM];     // 11.25 KB

    const int tid = threadIdx.x;
    const int b  = blockIdx.x / NQB;
    const int q0 = (blockIdx.x % NQB) * QPB;

    const float* lg = pred_logits + ((size_t)b * QDIM + q0) * CDIM;
    for (int i = tid; i < QPB * CDIM; i += 256) {
        float x = lg[i];
        s_cls[i] = 2.0f * __builtin_amdgcn_rcpf(1.0f + __expf(x));
    }
    __syncthreads();

    const int wave = tid >> 6;
    const int lane = tid & 63;

    // ---- target data in registers ----
    // slice A: lane owns t = 4*lane .. 4*lane+3  (t < 256)  -> float4 NT store
    // slice B: lane owns t = 256+lane (lane < 44)           -> scalar NT store
    const float4* tb4 = reinterpret_cast<const float4*>(tgt_boxes) + (size_t)b * TDIM;
    const int*    lb  = tgt_labels + (size_t)b * TDIM;

    TgtReg A[4];
    #pragma unroll
    for (int i = 0; i < 4; ++i) A[i] = load_tgt(tb4, lb, 4 * lane + i);

    const bool bok = lane < (TDIM - 256);            // lane < 44
    const int  tB  = bok ? (256 + lane) : (TDIM - 1);
    TgtReg Bt = load_tgt(tb4, lb, tB);

    const floatx2 neg1 = (floatx2){-1.0f, -1.0f};

    // ---- q loop: wave owns 9 contiguous q's ----
    const int qw = q0 + wave * QPW;
    const float4* pb4 = reinterpret_cast<const float4*>(pred_boxes) + (size_t)b * QDIM + qw;
    float* orow0 = out + ((size_t)b * QDIM + qw) * TDIM;

    #pragma unroll 1
    for (int j = 0; j < QPW; ++j) {
        float4 a = pb4[j];
        const float hw = 0.5f * a.z, hh = 0.5f * a.w;
        const floatx2 ap0n = (floatx2){hw - a.x, hh - a.y};
        const floatx2 ap1  = (floatx2){a.x + hw, a.y + hh};
        const floatx2 awh  = (floatx2){a.z, a.w};
        const floatx2 acc2 = (floatx2){a.x, a.y};
        const float area_a = a.z * a.w;
        const float* cls_j = s_cls + (wave * QPW + j) * CDIM;
        float* po = orow0 + j * TDIM;

        floatx4 res;
        res.x = cost_one(ap0n, ap1, awh, acc2, area_a, neg1, cls_j, A[0]);
        res.y = cost_one(ap0n, ap1, awh, acc2, area_a, neg1, cls_j, A[1]);
        res.z = cost_one(ap0n, ap1, awh, acc2, area_a, neg1, cls_j, A[2]);
        res.w = cost_one(ap0n, ap1, awh, acc2, area_a, neg1, cls_j, A[3]);
        __builtin_nontemporal_store(res, reinterpret_cast<floatx4*>(po) + lane);

        float cB = cost_one(ap0n, ap1, awh, acc2, area_a, neg1, cls_j, Bt);
        if (bok)
            __builtin_nontemporal_store(cB, po + 256 + lane);
    }
}

extern "C" void kernel_launch(void* const* d_in, const int* in_sizes, int n_in,
                              void* d_out, int out_size, void* d_ws, size_t ws_size,
                              hipStream_t stream) {
    const float* pred_logits = (const float*)d_in[0];
    const float* pred_boxes  = (const float*)d_in[1];
    const int*   tgt_labels  = (const int*)d_in[2];
    const float* tgt_boxes   = (const float*)d_in[3];
    float* out = (float*)d_out;

    const int B = in_sizes[0] / (QDIM * CDIM);   // 256
    dim3 grid(B * NQB);                          // 256 * 25 = 6400
    dim3 block(256);
    matcher_cost_kernel<<<grid, block, 0, stream>>>(pred_logits, pred_boxes,
                                                    tgt_labels, tgt_boxes, out);
}

// Round 11
// 90.513 us; speedup vs baseline: 1.0371x; 1.0371x over previous
//
#include <hip/hip_runtime.h>

// Problem constants (from reference setup_inputs)
#define QDIM 900
#define CDIM 80
#define TDIM 300
#define QPB 36               // q's per block (4 waves x 9)
#define QPW 9                // q's per wave
#define NQB (QDIM / QPB)     // 25 blocks per batch

typedef float floatx4 __attribute__((ext_vector_type(4)));  // native vector for NT store

struct TgtReg {
    float x0, y0, x1, y1;    // xyxy
    float cx, cy, w, h;      // cxcywh
    float area;
    int   lab;
};

__device__ __forceinline__ float cost_one(
    float ax0, float ay0, float ax1, float ay1,
    float acx, float acy, float aw, float ah, float area_a,
    const float* __restrict__ clsrow, const TgtReg& t)
{
    float clsv = clsrow[t.lab];

    // intersection (raw, unclamped) + enclosing via identity:
    //   cw = aw + bw - iw_raw,  ch = ah + bh - ih_raw
    float M0x = fmaxf(ax0, t.x0);
    float m1x = fminf(ax1, t.x1);
    float iwr = m1x - M0x;
    float iw  = fmaxf(iwr, 0.0f);
    float cw  = (aw + t.w) - iwr;

    float M0y = fmaxf(ay0, t.y0);
    float m1y = fminf(ay1, t.y1);
    float ihr = m1y - M0y;
    float ih  = fmaxf(ihr, 0.0f);
    float ch  = (ah + t.h) - ihr;

    float inter = iw * ih;
    float areac = cw * ch;
    float uni   = (area_a + t.area) - inter;

    // inter/uni + uni/areac = (inter*areac + uni^2) / (uni*areac)  -- one rcp
    float num   = fmaf(uni, uni, inter * areac);
    float den   = uni * areac;
    float ratio = num * __builtin_amdgcn_rcpf(den);

    // L1 in cxcywh
    float l1 = fabsf(acx - t.cx) + fabsf(acy - t.cy)
             + fabsf(aw - t.w)   + fabsf(ah - t.h);

    float acc = fmaf(5.0f, l1, clsv);
    return fmaf(-2.0f, ratio, acc);
}

__device__ __forceinline__ TgtReg load_tgt(const float4* tb4, const int* lb, int t)
{
    TgtReg r;
    float4 v = tb4[t];
    r.cx = v.x; r.cy = v.y; r.w = v.z; r.h = v.w;
    float hw = 0.5f * v.z, hh = 0.5f * v.w;
    r.x0 = v.x - hw; r.y0 = v.y - hh;
    r.x1 = v.x + hw; r.y1 = v.y + hh;
    r.area = v.z * v.w;
    r.lab = lb[t];
    return r;
}

__global__ __launch_bounds__(256, 4) void matcher_cost_kernel(
    const float* __restrict__ pred_logits,  // [B,Q,C]
    const float* __restrict__ pred_boxes,   // [B,Q,4] cxcywh
    const int*   __restrict__ tgt_labels,   // [B,T]
    const float* __restrict__ tgt_boxes,    // [B,T,4] cxcywh
    float* __restrict__ out)                // [B,Q,T]
{
    // s_cls[ql*C + c] = 2 - 2*sigmoid(logit) = 2/(1+e^x)
    // (the +2 comes from folding giou = iou - 1 + uni/areac)
    __shared__ float s_cls[QPB * CDIM];     // 11.25 KB

    const int tid = threadIdx.x;
    const int b  = blockIdx.x / NQB;
    const int q0 = (blockIdx.x % NQB) * QPB;

    const float* lg = pred_logits + ((size_t)b * QDIM + q0) * CDIM;
    for (int i = tid; i < QPB * CDIM; i += 256) {
        float x = lg[i];
        s_cls[i] = 2.0f * __builtin_amdgcn_rcpf(1.0f + __expf(x));
    }
    __syncthreads();

    const int wave = tid >> 6;
    const int lane = tid & 63;

    // ---- target data in registers ----
    // slice A: lane owns t = 4*lane .. 4*lane+3  (t < 256)  -> float4 NT store
    // slice B: lane owns t = 256+lane (lane < 44)           -> scalar NT store
    const float4* tb4 = reinterpret_cast<const float4*>(tgt_boxes) + (size_t)b * TDIM;
    const int*    lb  = tgt_labels + (size_t)b * TDIM;

    TgtReg A[4];
    #pragma unroll
    for (int i = 0; i < 4; ++i) A[i] = load_tgt(tb4, lb, 4 * lane + i);

    const bool bok = lane < (TDIM - 256);            // lane < 44
    const int  tB  = bok ? (256 + lane) : (TDIM - 1);
    TgtReg Bt = load_tgt(tb4, lb, tB);

    // ---- q loop: wave owns 9 contiguous q's ----
    // FULLY UNROLLED: each j gets its own result registers, stores issued
    // inline with no register reuse -> compiler only needs vmcnt waits at
    // long reuse distance, hiding the NT-store ack latency.
    const int qw = q0 + wave * QPW;
    const float4* pb4 = reinterpret_cast<const float4*>(pred_boxes) + (size_t)b * QDIM + qw;
    float* orow0 = out + ((size_t)b * QDIM + qw) * TDIM;

    #pragma unroll
    for (int j = 0; j < QPW; ++j) {
        float4 a = pb4[j];
        const float hw = 0.5f * a.z, hh = 0.5f * a.w;
        const float ax0 = a.x - hw, ay0 = a.y - hh;
        const float ax1 = a.x + hw, ay1 = a.y + hh;
        const float area_a = a.z * a.w;
        const float* clsrow = s_cls + (wave * QPW + j) * CDIM;
        float* po = orow0 + j * TDIM;

        floatx4 res;
        res.x = cost_one(ax0, ay0, ax1, ay1, a.x, a.y, a.z, a.w, area_a, clsrow, A[0]);
        res.y = cost_one(ax0, ay0, ax1, ay1, a.x, a.y, a.z, a.w, area_a, clsrow, A[1]);
        res.z = cost_one(ax0, ay0, ax1, ay1, a.x, a.y, a.z, a.w, area_a, clsrow, A[2]);
        res.w = cost_one(ax0, ay0, ax1, ay1, a.x, a.y, a.z, a.w, area_a, clsrow, A[3]);
        __builtin_nontemporal_store(res, reinterpret_cast<floatx4*>(po) + lane);

        float cB = cost_one(ax0, ay0, ax1, ay1, a.x, a.y, a.z, a.w, area_a, clsrow, Bt);
        if (bok)
            __builtin_nontemporal_store(cB, po + 256 + lane);
    }
}

extern "C" void kernel_launch(void* const* d_in, const int* in_sizes, int n_in,
                              void* d_out, int out_size, void* d_ws, size_t ws_size,
                              hipStream_t stream) {
    const float* pred_logits = (const float*)d_in[0];
    const float* pred_boxes  = (const float*)d_in[1];
    const int*   tgt_labels  = (const int*)d_in[2];
    const float* tgt_boxes   = (const float*)d_in[3];
    float* out = (float*)d_out;

    const int B = in_sizes[0] / (QDIM * CDIM);   // 256
    dim3 grid(B * NQB);                          // 256 * 25 = 6400
    dim3 block(256);
    matcher_cost_kernel<<<grid, block, 0, stream>>>(pred_logits, pred_boxes,
                                                    tgt_labels, tgt_boxes, out);
}

// Round 12
// 81.640 us; speedup vs baseline: 1.1498x; 1.1087x over previous
//
#include <hip/hip_runtime.h>

// Problem constants (from reference setup_inputs)
#define QDIM 900
#define CDIM 80
#define TDIM 300
#define QPB 36               // q's per block (4 waves x 9)
#define QPW 9                // q's per wave
#define NQB (QDIM / QPB)     // 25 blocks per batch

typedef float floatx4 __attribute__((ext_vector_type(4)));  // native vector for NT store

struct TgtReg {
    float x0, y0, x1, y1;    // xyxy
    float cx, cy, w, h;      // cxcywh
    float area;
    int   lab;
};

__device__ __forceinline__ float cost_one(
    float ax0, float ay0, float ax1, float ay1,
    float acx, float acy, float aw, float ah, float area_a,
    const float* __restrict__ clsrow, const TgtReg& t)
{
    float clsv = clsrow[t.lab];

    // intersection (raw, unclamped) + enclosing via identity:
    //   cw = aw + bw - iw_raw,  ch = ah + bh - ih_raw
    float M0x = fmaxf(ax0, t.x0);
    float m1x = fminf(ax1, t.x1);
    float iwr = m1x - M0x;
    float iw  = fmaxf(iwr, 0.0f);
    float cw  = (aw + t.w) - iwr;

    float M0y = fmaxf(ay0, t.y0);
    float m1y = fminf(ay1, t.y1);
    float ihr = m1y - M0y;
    float ih  = fmaxf(ihr, 0.0f);
    float ch  = (ah + t.h) - ihr;

    float inter = iw * ih;
    float areac = cw * ch;
    float uni   = (area_a + t.area) - inter;

    // inter/uni + uni/areac = (inter*areac + uni^2) / (uni*areac)  -- one rcp
    float num   = fmaf(uni, uni, inter * areac);
    float den   = uni * areac;
    float ratio = num * __builtin_amdgcn_rcpf(den);

    // L1 in cxcywh
    float l1 = fabsf(acx - t.cx) + fabsf(acy - t.cy)
             + fabsf(aw - t.w)   + fabsf(ah - t.h);

    float acc = fmaf(5.0f, l1, clsv);
    return fmaf(-2.0f, ratio, acc);
}

__device__ __forceinline__ TgtReg load_tgt(const float4* tb4, const int* lb, int t)
{
    TgtReg r;
    float4 v = tb4[t];
    r.cx = v.x; r.cy = v.y; r.w = v.z; r.h = v.w;
    float hw = 0.5f * v.z, hh = 0.5f * v.w;
    r.x0 = v.x - hw; r.y0 = v.y - hh;
    r.x1 = v.x + hw; r.y1 = v.y + hh;
    r.area = v.z * v.w;
    r.lab = lb[t];
    return r;
}

__global__ __launch_bounds__(256, 4) void matcher_cost_kernel(
    const float* __restrict__ pred_logits,  // [B,Q,C]
    const float* __restrict__ pred_boxes,   // [B,Q,4] cxcywh
    const int*   __restrict__ tgt_labels,   // [B,T]
    const float* __restrict__ tgt_boxes,    // [B,T,4] cxcywh
    float* __restrict__ out)                // [B,Q,T]
{
    // s_cls[ql*C + c] = 2 - 2*sigmoid(logit) = 2/(1+e^x)
    // (the +2 comes from folding giou = iou - 1 + uni/areac)
    __shared__ float s_cls[QPB * CDIM];     // 11.25 KB

    const int tid = threadIdx.x;
    const int b  = blockIdx.x / NQB;
    const int q0 = (blockIdx.x % NQB) * QPB;

    const float* lg = pred_logits + ((size_t)b * QDIM + q0) * CDIM;
    for (int i = tid; i < QPB * CDIM; i += 256) {
        float x = lg[i];
        s_cls[i] = 2.0f * __builtin_amdgcn_rcpf(1.0f + __expf(x));
    }
    __syncthreads();

    const int wave = tid >> 6;
    const int lane = tid & 63;

    // ---- target data in registers ----
    // slice A: lane owns t = 4*lane .. 4*lane+3  (t < 256)  -> float4 NT store
    // slice B: lane owns t = 256+lane (lane < 44)           -> scalar NT store
    const float4* tb4 = reinterpret_cast<const float4*>(tgt_boxes) + (size_t)b * TDIM;
    const int*    lb  = tgt_labels + (size_t)b * TDIM;

    TgtReg A[4];
    #pragma unroll
    for (int i = 0; i < 4; ++i) A[i] = load_tgt(tb4, lb, 4 * lane + i);

    const bool bok = lane < (TDIM - 256);            // lane < 44
    const int  tB  = bok ? (256 + lane) : (TDIM - 1);
    TgtReg Bt = load_tgt(tb4, lb, tB);

    // ---- CRITICAL: hoist ALL pred-box loads before ANY store is issued ----
    // vmcnt is a single in-order FIFO shared by loads and stores: a load
    // issued after NT stores forces a drain of those stores at its first
    // use. With zero VMEM loads after this prologue, stores are never
    // waited on and stream at full depth.
    const int qw = q0 + wave * QPW;
    const float4* pb4 = reinterpret_cast<const float4*>(pred_boxes) + (size_t)b * QDIM + qw;
    float4 abox[QPW];
    #pragma unroll
    for (int j = 0; j < QPW; ++j) abox[j] = pb4[j];

    float* orow0 = out + ((size_t)b * QDIM + qw) * TDIM;

    #pragma unroll
    for (int j = 0; j < QPW; ++j) {
        float4 a = abox[j];
        const float hw = 0.5f * a.z, hh = 0.5f * a.w;
        const float ax0 = a.x - hw, ay0 = a.y - hh;
        const float ax1 = a.x + hw, ay1 = a.y + hh;
        const float area_a = a.z * a.w;
        const float* clsrow = s_cls + (wave * QPW + j) * CDIM;
        float* po = orow0 + j * TDIM;

        floatx4 res;
        res.x = cost_one(ax0, ay0, ax1, ay1, a.x, a.y, a.z, a.w, area_a, clsrow, A[0]);
        res.y = cost_one(ax0, ay0, ax1, ay1, a.x, a.y, a.z, a.w, area_a, clsrow, A[1]);
        res.z = cost_one(ax0, ay0, ax1, ay1, a.x, a.y, a.z, a.w, area_a, clsrow, A[2]);
        res.w = cost_one(ax0, ay0, ax1, ay1, a.x, a.y, a.z, a.w, area_a, clsrow, A[3]);
        __builtin_nontemporal_store(res, reinterpret_cast<floatx4*>(po) + lane);

        float cB = cost_one(ax0, ay0, ax1, ay1, a.x, a.y, a.z, a.w, area_a, clsrow, Bt);
        if (bok)
            __builtin_nontemporal_store(cB, po + 256 + lane);
    }
}

extern "C" void kernel_launch(void* const* d_in, const int* in_sizes, int n_in,
                              void* d_out, int out_size, void* d_ws, size_t ws_size,
                              hipStream_t stream) {
    const float* pred_logits = (const float*)d_in[0];
    const float* pred_boxes  = (const float*)d_in[1];
    const int*   tgt_labels  = (const int*)d_in[2];
    const float* tgt_boxes   = (const float*)d_in[3];
    float* out = (float*)d_out;

    const int B = in_sizes[0] / (QDIM * CDIM);   // 256
    dim3 grid(B * NQB);                          // 256 * 25 = 6400
    dim3 block(256);
    matcher_cost_kernel<<<grid, block, 0, stream>>>(pred_logits, pred_boxes,
                                                    tgt_labels, tgt_boxes, out);
}

// Round 14
// 79.333 us; speedup vs baseline: 1.1833x; 1.0291x over previous
//
#include <hip/hip_runtime.h>

// Problem constants (from reference setup_inputs)
#define QDIM 900
#define CDIM 80
#define TDIM 300
#define QPB 36               // q's per block (4 waves x 9)
#define QPW 9                // q's per wave
#define NQB (QDIM / QPB)     // 25 blocks per batch

typedef float  floatx4 __attribute__((ext_vector_type(4)));
typedef __fp16 h2      __attribute__((ext_vector_type(2)));   // matches cvt_pkrtz return type

__device__ __forceinline__ h2 h2dup(float v) {            // splat f32 -> (f16,f16)
    return __builtin_amdgcn_cvt_pkrtz(v, v);
}
__device__ __forceinline__ h2 h2pk(float a, float b) {    // pack two f32 -> h2
    return __builtin_amdgcn_cvt_pkrtz(a, b);
}
__device__ __forceinline__ h2 h2abs(h2 x) {
    unsigned u = __builtin_bit_cast(unsigned, x) & 0x7FFF7FFFu;
    return __builtin_bit_cast(h2, u);
}
__device__ __forceinline__ h2 h2min(h2 a, h2 b) { return __builtin_elementwise_min(a, b); }
__device__ __forceinline__ h2 h2max(h2 a, h2 b) { return __builtin_elementwise_max(a, b); }

// Two targets packed per h2 lane-register (element .x = t_even, .y = t_odd)
struct TgtPair {
    h2 x0, y0, x1, y1;   // xyxy corners
    h2 w, h, cx, cy;     // cxcywh
    h2 area;
    int lab0, lab1;
};

// Query box broadcast into h2 (both halves identical)
struct AH {
    h2 x0, y0, x1, y1, w, h, cx, cy, area;
};

// f32 tail target (slice B), identical math to R12
struct TgtReg {
    float x0, y0, x1, y1;
    float cx, cy, w, h;
    float area;
    int   lab;
};

// Packed-f16 geometry, f32 ratio/rcp (f16 rcp can't span 1/den range).
__device__ __forceinline__ void cost_pair(
    const AH& a, const TgtPair& t, const float* __restrict__ clsrow,
    float* out0, float* out1)
{
    h2 M0x  = h2max(a.x0, t.x0);
    h2 m1x  = h2min(a.x1, t.x1);
    h2 iwrx = m1x - M0x;
    h2 cwx  = (a.w + t.w) - iwrx;      // enclosing identity
    h2 M0y  = h2max(a.y0, t.y0);
    h2 m1y  = h2min(a.y1, t.y1);
    h2 ihry = m1y - M0y;
    h2 cwy  = (a.h + t.h) - ihry;

    h2 zero = (h2)0;
    h2 iw = h2max(iwrx, zero);
    h2 ih = h2max(ihry, zero);

    h2 inter = iw * ih;
    h2 areac = cwx * cwy;
    h2 uni   = (a.area + t.area) - inter;

    h2 l1 = (h2abs(a.cx - t.cx) + h2abs(a.cy - t.cy))
          + (h2abs(a.w  - t.w ) + h2abs(a.h  - t.h ));

    float cls0 = clsrow[t.lab0];
    float cls1 = clsrow[t.lab1];

    // cvt up; ratio in f32 (single fast rcp per element)
    float i0 = (float)inter.x, i1 = (float)inter.y;
    float u0 = (float)uni.x,   u1 = (float)uni.y;
    float c0 = (float)areac.x, c1 = (float)areac.y;
    float L0 = (float)l1.x,    L1 = (float)l1.y;

    float num0 = fmaf(u0, u0, i0 * c0);
    float num1 = fmaf(u1, u1, i1 * c1);
    float r0 = num0 * __builtin_amdgcn_rcpf(u0 * c0);
    float r1 = num1 * __builtin_amdgcn_rcpf(u1 * c1);

    float a0 = fmaf(5.0f, L0, cls0);
    float a1 = fmaf(5.0f, L1, cls1);
    *out0 = fmaf(-2.0f, r0, a0);
    *out1 = fmaf(-2.0f, r1, a1);
}

// f32 scalar path for the tail element (identical to R12)
__device__ __forceinline__ float cost_one(
    float ax0, float ay0, float ax1, float ay1,
    float acx, float acy, float aw, float ah, float area_a,
    const float* __restrict__ clsrow, const TgtReg& t)
{
    float clsv = clsrow[t.lab];
    float M0x = fmaxf(ax0, t.x0);
    float m1x = fminf(ax1, t.x1);
    float iwr = m1x - M0x;
    float iw  = fmaxf(iwr, 0.0f);
    float cw  = (aw + t.w) - iwr;
    float M0y = fmaxf(ay0, t.y0);
    float m1y = fminf(ay1, t.y1);
    float ihr = m1y - M0y;
    float ih  = fmaxf(ihr, 0.0f);
    float ch  = (ah + t.h) - ihr;
    float inter = iw * ih;
    float areac = cw * ch;
    float uni   = (area_a + t.area) - inter;
    float num   = fmaf(uni, uni, inter * areac);
    float den   = uni * areac;
    float ratio = num * __builtin_amdgcn_rcpf(den);
    float l1 = fabsf(acx - t.cx) + fabsf(acy - t.cy)
             + fabsf(aw - t.w)   + fabsf(ah - t.h);
    float acc = fmaf(5.0f, l1, clsv);
    return fmaf(-2.0f, ratio, acc);
}

__device__ __forceinline__ TgtPair make_pair(float4 v0, float4 v1, int l0, int l1)
{
    TgtPair p;
    float hw0 = 0.5f * v0.z, hh0 = 0.5f * v0.w;
    float hw1 = 0.5f * v1.z, hh1 = 0.5f * v1.w;
    p.x0 = h2pk(v0.x - hw0, v1.x - hw1);
    p.y0 = h2pk(v0.y - hh0, v1.y - hh1);
    p.x1 = h2pk(v0.x + hw0, v1.x + hw1);
    p.y1 = h2pk(v0.y + hh0, v1.y + hh1);
    p.w  = h2pk(v0.z, v1.z);
    p.h  = h2pk(v0.w, v1.w);
    p.cx = h2pk(v0.x, v1.x);
    p.cy = h2pk(v0.y, v1.y);
    p.area = h2pk(v0.z * v0.w, v1.z * v1.w);
    p.lab0 = l0; p.lab1 = l1;
    return p;
}

__global__ __launch_bounds__(256, 4) void matcher_cost_kernel(
    const float* __restrict__ pred_logits,  // [B,Q,C]
    const float* __restrict__ pred_boxes,   // [B,Q,4] cxcywh
    const int*   __restrict__ tgt_labels,   // [B,T]
    const float* __restrict__ tgt_boxes,    // [B,T,4] cxcywh
    float* __restrict__ out)                // [B,Q,T]
{
    // s_cls[ql*C + c] = 2 - 2*sigmoid(logit) = 2/(1+e^x)
    __shared__ float s_cls[QPB * CDIM];     // 11.25 KB

    const int tid = threadIdx.x;
    const int b  = blockIdx.x / NQB;
    const int q0 = (blockIdx.x % NQB) * QPB;

    const float* lg = pred_logits + ((size_t)b * QDIM + q0) * CDIM;
    for (int i = tid; i < QPB * CDIM; i += 256) {
        float x = lg[i];
        s_cls[i] = 2.0f * __builtin_amdgcn_rcpf(1.0f + __expf(x));
    }
    __syncthreads();

    const int wave = tid >> 6;
    const int lane = tid & 63;

    // ---- target data: slice A (t = 4*lane..4*lane+3) packed f16 pairs,
    //      slice B tail (t = 256+lane, lane<44) in f32 ----
    const float4* tb4 = reinterpret_cast<const float4*>(tgt_boxes) + (size_t)b * TDIM;
    const int*    lb  = tgt_labels + (size_t)b * TDIM;

    float4 v0 = tb4[4 * lane + 0];
    float4 v1 = tb4[4 * lane + 1];
    float4 v2 = tb4[4 * lane + 2];
    float4 v3 = tb4[4 * lane + 3];
    int4   lq = reinterpret_cast<const int4*>(lb)[lane];

    const bool bok = lane < (TDIM - 256);            // lane < 44
    const int  tB  = bok ? (256 + lane) : (TDIM - 1);
    float4 vB = tb4[tB];
    int    lB = lb[tB];

    TgtPair P01 = make_pair(v0, v1, lq.x, lq.y);
    TgtPair P23 = make_pair(v2, v3, lq.z, lq.w);

    TgtReg Bt;
    {
        float hw = 0.5f * vB.z, hh = 0.5f * vB.w;
        Bt.cx = vB.x; Bt.cy = vB.y; Bt.w = vB.z; Bt.h = vB.w;
        Bt.x0 = vB.x - hw; Bt.y0 = vB.y - hh;
        Bt.x1 = vB.x + hw; Bt.y1 = vB.y + hh;
        Bt.area = vB.z * vB.w;
        Bt.lab = lB;
    }

    // ---- hoist ALL pred-box loads before ANY store (vmcnt FIFO: a load
    //      issued after stores forces a store drain at first use) ----
    const int qw = q0 + wave * QPW;
    const float4* pb4 = reinterpret_cast<const float4*>(pred_boxes) + (size_t)b * QDIM + qw;
    float4 abox[QPW];
    #pragma unroll
    for (int j = 0; j < QPW; ++j) abox[j] = pb4[j];

    float* orow0 = out + ((size_t)b * QDIM + qw) * TDIM;

    #pragma unroll
    for (int j = 0; j < QPW; ++j) {
        float4 a = abox[j];
        const float hw = 0.5f * a.z, hh = 0.5f * a.w;
        const float ax0 = a.x - hw, ay0 = a.y - hh;
        const float ax1 = a.x + hw, ay1 = a.y + hh;
        const float area_a = a.z * a.w;

        AH ah;
        ah.x0 = h2dup(ax0);  ah.y0 = h2dup(ay0);
        ah.x1 = h2dup(ax1);  ah.y1 = h2dup(ay1);
        ah.w  = h2dup(a.z);  ah.h  = h2dup(a.w);
        ah.cx = h2dup(a.x);  ah.cy = h2dup(a.y);
        ah.area = h2dup(area_a);

        const float* clsrow = s_cls + (wave * QPW + j) * CDIM;
        float* po = orow0 + j * TDIM;

        float r0, r1, r2, r3;
        cost_pair(ah, P01, clsrow, &r0, &r1);
        cost_pair(ah, P23, clsrow, &r2, &r3);
        floatx4 res = {r0, r1, r2, r3};
        __builtin_nontemporal_store(res, reinterpret_cast<floatx4*>(po) + lane);

        float cB = cost_one(ax0, ay0, ax1, ay1, a.x, a.y, a.z, a.w, area_a, clsrow, Bt);
        if (bok)
            __builtin_nontemporal_store(cB, po + 256 + lane);
    }
}

extern "C" void kernel_launch(void* const* d_in, const int* in_sizes, int n_in,
                              void* d_out, int out_size, void* d_ws, size_t ws_size,
                              hipStream_t stream) {
    const float* pred_logits = (const float*)d_in[0];
    const float* pred_boxes  = (const float*)d_in[1];
    const int*   tgt_labels  = (const int*)d_in[2];
    const float* tgt_boxes   = (const float*)d_in[3];
    float* out = (float*)d_out;

    const int B = in_sizes[0] / (QDIM * CDIM);   // 256
    dim3 grid(B * NQB);                          // 256 * 25 = 6400
    dim3 block(256);
    matcher_cost_kernel<<<grid, block, 0, stream>>>(pred_logits, pred_boxes,
                                                    tgt_labels, tgt_boxes, out);
}

// Round 15
// 78.323 us; speedup vs baseline: 1.1986x; 1.0129x over previous
//
#include <hip/hip_runtime.h>

// Problem constants (from reference setup_inputs)
#define QDIM 900
#define CDIM 80
#define TDIM 300
#define QPB 36               // q's per block (4 waves x 9)
#define QPW 9                // q's per wave
#define NQB (QDIM / QPB)     // 25 blocks per batch

typedef float  floatx4 __attribute__((ext_vector_type(4)));
typedef __fp16 h2      __attribute__((ext_vector_type(2)));   // matches cvt_pkrtz return type

__device__ __forceinline__ h2 h2dup(float v) {            // splat f32 -> (f16,f16)
    return __builtin_amdgcn_cvt_pkrtz(v, v);
}
__device__ __forceinline__ h2 h2pk(float a, float b) {    // pack two f32 -> h2
    return __builtin_amdgcn_cvt_pkrtz(a, b);
}
__device__ __forceinline__ h2 h2abs(h2 x) {
    unsigned u = __builtin_bit_cast(unsigned, x) & 0x7FFF7FFFu;
    return __builtin_bit_cast(h2, u);
}
__device__ __forceinline__ h2 h2min(h2 a, h2 b) { return __builtin_elementwise_min(a, b); }
__device__ __forceinline__ h2 h2max(h2 a, h2 b) { return __builtin_elementwise_max(a, b); }

// ---- v_fma_mix_f32: f32 result from f16 operands (exact cvt + f32 FMA) ----
// op_sel_hi=1,op_sel=0 -> low f16 half; op_sel=1 -> high f16 half; 00 -> f32.
__device__ __forceinline__ float mixmul_lo(h2 a, h2 b) {
    float d;
    asm("v_fma_mix_f32 %0, %1, %2, 0 op_sel:[0,0,0] op_sel_hi:[1,1,0]"
        : "=v"(d) : "v"(a), "v"(b));
    return d;
}
__device__ __forceinline__ float mixmul_hi(h2 a, h2 b) {
    float d;
    asm("v_fma_mix_f32 %0, %1, %2, 0 op_sel:[1,1,0] op_sel_hi:[1,1,0]"
        : "=v"(d) : "v"(a), "v"(b));
    return d;
}
__device__ __forceinline__ float mixfma_lo(h2 a, h2 b, float c) {
    float d;
    asm("v_fma_mix_f32 %0, %1, %2, %3 op_sel:[0,0,0] op_sel_hi:[1,1,0]"
        : "=v"(d) : "v"(a), "v"(b), "v"(c));
    return d;
}
__device__ __forceinline__ float mixfma_hi(h2 a, h2 b, float c) {
    float d;
    asm("v_fma_mix_f32 %0, %1, %2, %3 op_sel:[1,1,0] op_sel_hi:[1,1,0]"
        : "=v"(d) : "v"(a), "v"(b), "v"(c));
    return d;
}
// a.f16(lo/hi) * b.f32 + c.f32
__device__ __forceinline__ float mixfma_lo_fb(h2 a, float b, float c) {
    float d;
    asm("v_fma_mix_f32 %0, %1, %2, %3 op_sel:[0,0,0] op_sel_hi:[1,0,0]"
        : "=v"(d) : "v"(a), "v"(b), "v"(c));
    return d;
}
__device__ __forceinline__ float mixfma_hi_fb(h2 a, float b, float c) {
    float d;
    asm("v_fma_mix_f32 %0, %1, %2, %3 op_sel:[1,0,0] op_sel_hi:[1,0,0]"
        : "=v"(d) : "v"(a), "v"(b), "v"(c));
    return d;
}

// Two targets packed per h2 lane-register (element .x = t_even, .y = t_odd)
struct TgtPair {
    h2 x0, y0, x1, y1;   // xyxy corners
    h2 w, h, cx, cy;     // cxcywh
    h2 area;
    int lab0, lab1;
};

// Query box broadcast into h2 (both halves identical)
struct AH {
    h2 x0, y0, x1, y1, w, h, cx, cy, area;
};

// Packed-f16 geometry; ratio path via v_fma_mix (no cvt instructions).
__device__ __forceinline__ void cost_pair(
    const AH& a, const TgtPair& t, const float* __restrict__ clsrow,
    float five, float* out0, float* out1)
{
    h2 M0x  = h2max(a.x0, t.x0);
    h2 m1x  = h2min(a.x1, t.x1);
    h2 iwrx = m1x - M0x;
    h2 cwx  = (a.w + t.w) - iwrx;      // enclosing identity
    h2 M0y  = h2max(a.y0, t.y0);
    h2 m1y  = h2min(a.y1, t.y1);
    h2 ihry = m1y - M0y;
    h2 cwy  = (a.h + t.h) - ihry;

    h2 zero = (h2)0;
    h2 iw = h2max(iwrx, zero);
    h2 ih = h2max(ihry, zero);

    h2 inter = iw * ih;
    h2 areac = cwx * cwy;
    h2 uni   = (a.area + t.area) - inter;

    h2 l1 = (h2abs(a.cx - t.cx) + h2abs(a.cy - t.cy))
          + (h2abs(a.w  - t.w ) + h2abs(a.h  - t.h ));

    float cls0 = clsrow[t.lab0];
    float cls1 = clsrow[t.lab1];

    // den = uni*areac ; num = uni^2 + inter*areac  (all f32 via fma_mix)
    float den0 = mixmul_lo(uni, areac);
    float den1 = mixmul_hi(uni, areac);
    float t0   = mixmul_lo(inter, areac);
    float t1   = mixmul_hi(inter, areac);
    float num0 = mixfma_lo(uni, uni, t0);
    float num1 = mixfma_hi(uni, uni, t1);

    float r0 = num0 * __builtin_amdgcn_rcpf(den0);
    float r1 = num1 * __builtin_amdgcn_rcpf(den1);

    float a0 = mixfma_lo_fb(l1, five, cls0);   // 5*l1 + cls
    float a1 = mixfma_hi_fb(l1, five, cls1);
    *out0 = fmaf(-2.0f, r0, a0);
    *out1 = fmaf(-2.0f, r1, a1);
}

__device__ __forceinline__ TgtPair make_pair(float4 v0, float4 v1, int l0, int l1)
{
    TgtPair p;
    float hw0 = 0.5f * v0.z, hh0 = 0.5f * v0.w;
    float hw1 = 0.5f * v1.z, hh1 = 0.5f * v1.w;
    p.x0 = h2pk(v0.x - hw0, v1.x - hw1);
    p.y0 = h2pk(v0.y - hh0, v1.y - hh1);
    p.x1 = h2pk(v0.x + hw0, v1.x + hw1);
    p.y1 = h2pk(v0.y + hh0, v1.y + hh1);
    p.w  = h2pk(v0.z, v1.z);
    p.h  = h2pk(v0.w, v1.w);
    p.cx = h2pk(v0.x, v1.x);
    p.cy = h2pk(v0.y, v1.y);
    p.area = h2pk(v0.z * v0.w, v1.z * v1.w);
    p.lab0 = l0; p.lab1 = l1;
    return p;
}

__global__ __launch_bounds__(256, 4) void matcher_cost_kernel(
    const float* __restrict__ pred_logits,  // [B,Q,C]
    const float* __restrict__ pred_boxes,   // [B,Q,4] cxcywh
    const int*   __restrict__ tgt_labels,   // [B,T]
    const float* __restrict__ tgt_boxes,    // [B,T,4] cxcywh
    float* __restrict__ out)                // [B,Q,T]
{
    // s_cls[ql*C + c] = 2 - 2*sigmoid(logit) = 2/(1+e^x)
    __shared__ float s_cls[QPB * CDIM];     // 11.25 KB

    const int tid = threadIdx.x;
    const int b  = blockIdx.x / NQB;
    const int q0 = (blockIdx.x % NQB) * QPB;

    const float* lg = pred_logits + ((size_t)b * QDIM + q0) * CDIM;
    for (int i = tid; i < QPB * CDIM; i += 256) {
        float x = lg[i];
        s_cls[i] = 2.0f * __builtin_amdgcn_rcpf(1.0f + __expf(x));
    }
    __syncthreads();

    const int wave = tid >> 6;
    const int lane = tid & 63;

    // ---- target data: slice A (t = 4*lane..4*lane+3) as 2 packed f16 pairs,
    //      slice B tail (t = 256+lane, lane<44) as a duplicated pair ----
    const float4* tb4 = reinterpret_cast<const float4*>(tgt_boxes) + (size_t)b * TDIM;
    const int*    lb  = tgt_labels + (size_t)b * TDIM;

    float4 v0 = tb4[4 * lane + 0];
    float4 v1 = tb4[4 * lane + 1];
    float4 v2 = tb4[4 * lane + 2];
    float4 v3 = tb4[4 * lane + 3];
    int4   lq = reinterpret_cast<const int4*>(lb)[lane];

    const bool bok = lane < (TDIM - 256);            // lane < 44
    const int  tB  = bok ? (256 + lane) : (TDIM - 1);
    float4 vB = tb4[tB];
    int    lB = lb[tB];

    TgtPair P01 = make_pair(v0, v1, lq.x, lq.y);
    TgtPair P23 = make_pair(v2, v3, lq.z, lq.w);
    TgtPair PB  = make_pair(vB, vB, lB, lB);     // tail duplicated; out1 ignored

    // ---- hoist ALL pred-box loads before ANY store (vmcnt FIFO: a load
    //      issued after stores forces a store drain at first use) ----
    const int qw = q0 + wave * QPW;
    const float4* pb4 = reinterpret_cast<const float4*>(pred_boxes) + (size_t)b * QDIM + qw;
    float4 abox[QPW];
    #pragma unroll
    for (int j = 0; j < QPW; ++j) abox[j] = pb4[j];

    float* orow0 = out + ((size_t)b * QDIM + qw) * TDIM;
    const float five = 5.0f;

    #pragma unroll
    for (int j = 0; j < QPW; ++j) {
        float4 a = abox[j];
        const float hw = 0.5f * a.z, hh = 0.5f * a.w;
        const float area_a = a.z * a.w;

        AH ah;
        ah.x0 = h2dup(a.x - hw);  ah.y0 = h2dup(a.y - hh);
        ah.x1 = h2dup(a.x + hw);  ah.y1 = h2dup(a.y + hh);
        ah.w  = h2dup(a.z);       ah.h  = h2dup(a.w);
        ah.cx = h2dup(a.x);       ah.cy = h2dup(a.y);
        ah.area = h2dup(area_a);

        const float* clsrow = s_cls + (wave * QPW + j) * CDIM;
        float* po = orow0 + j * TDIM;

        float r0, r1, r2, r3;
        cost_pair(ah, P01, clsrow, five, &r0, &r1);
        cost_pair(ah, P23, clsrow, five, &r2, &r3);
        floatx4 res = {r0, r1, r2, r3};
        __builtin_nontemporal_store(res, reinterpret_cast<floatx4*>(po) + lane);

        float cB, cDummy;
        cost_pair(ah, PB, clsrow, five, &cB, &cDummy);
        if (bok)
            __builtin_nontemporal_store(cB, po + 256 + lane);
    }
}

extern "C" void kernel_launch(void* const* d_in, const int* in_sizes, int n_in,
                              void* d_out, int out_size, void* d_ws, size_t ws_size,
                              hipStream_t stream) {
    const float* pred_logits = (const float*)d_in[0];
    const float* pred_boxes  = (const float*)d_in[1];
    const int*   tgt_labels  = (const int*)d_in[2];
    const float* tgt_boxes   = (const float*)d_in[3];
    float* out = (float*)d_out;

    const int B = in_sizes[0] / (QDIM * CDIM);   // 256
    dim3 grid(B * NQB);                          // 256 * 25 = 6400
    dim3 block(256);
    matcher_cost_kernel<<<grid, block, 0, stream>>>(pred_logits, pred_boxes,
                                                    tgt_labels, tgt_boxes, out);
}